// Round 5
// baseline (201.219 us; speedup 1.0000x reference)
//
#include <hip/hip_runtime.h>

#define IN_DIM 128
#define NCOL   256   // UV row: [U(128) | V(128)], bf16

typedef __bf16 bfx8 __attribute__((ext_vector_type(8)));
typedef __bf16 bfx4 __attribute__((ext_vector_type(4)));
typedef float  f32x4 __attribute__((ext_vector_type(4)));

// ---------------- GEMM: UV = bf16( z @ Weff^T + [b1|0] ) ----------------
// Weff[n][k] = (n<128) ? W1[n][k] : W1[n-128][128+k]  (W1 is [128][256] fp32)
// M=100000, K=128, N=256.  MFMA 16x16x32 bf16 with OPERANDS SWAPPED:
//   acc = mfma(wfrag, zfrag, acc)  ->  D[row=q*4+r -> n][col=l15 -> m]
// so each lane's acc f32x4 is 4 CONSECUTIVE n-values of one m-row:
// epilogue is 4 direct 8 B global stores per chunk. No LDS, no barriers.
// Block = 256 thr = 4 waves; wave w owns n-slice [w*64, w*64+64).
// Block covers 32 m-rows as 2 chunks of 16; grid 3125.
__global__ __launch_bounds__(256) void gemm_mfma(
    const float* __restrict__ z, const float* __restrict__ W1,
    const float* __restrict__ b1, __bf16* __restrict__ UV, int M)
{
    const int tid  = threadIdx.x;
    const int wave = tid >> 6;
    const int lane = tid & 63;
    const int l15  = lane & 15;
    const int q    = lane >> 4;        // quad 0..3
    const int n0   = wave * 64;
    const int m0   = blockIdx.x * 32;  // M % 32 == 0

    // --- Weff fragments (first mfma operand): lane holds Weff[n][kk*32+q*8 ..+8]
    //     n = n0 + nt*16 + l15.  Waves read disjoint 64-row slices of Weff.
    bfx8 wfrag[4][4];
#pragma unroll
    for (int nt = 0; nt < 4; ++nt) {
        const int n = n0 + nt * 16 + l15;
#pragma unroll
        for (int kk = 0; kk < 4; ++kk) {
            const int k = kk * 32 + q * 8;
            const float* p = (n < 128) ? (W1 + n * 256 + k)
                                       : (W1 + (n - 128) * 256 + 128 + k);
            float4 f0 = *(const float4*)p;
            float4 f1 = *(const float4*)(p + 4);
            bfx8 w;
            w[0] = (__bf16)f0.x; w[1] = (__bf16)f0.y; w[2] = (__bf16)f0.z; w[3] = (__bf16)f0.w;
            w[4] = (__bf16)f1.x; w[5] = (__bf16)f1.y; w[6] = (__bf16)f1.z; w[7] = (__bf16)f1.w;
            wfrag[nt][kk] = w;
        }
    }

    // --- bias: lane covers n = n0+nt*16+q*4 .. +4 (V half gets 0) ---
    f32x4 bias[4];
#pragma unroll
    for (int nt = 0; nt < 4; ++nt) {
        const int nb = n0 + nt * 16 + q * 4;
        if (nb < 128) {
            float4 b = *(const float4*)(b1 + nb);
            bias[nt] = (f32x4){b.x, b.y, b.z, b.w};
        } else {
            bias[nt] = (f32x4){0.f, 0.f, 0.f, 0.f};
        }
    }

    // --- 2 chunks of 16 m-rows; no barriers -> compiler pipelines freely ---
#pragma unroll
    for (int c = 0; c < 2; ++c) {
        const int m = m0 + c * 16 + l15;

        // z fragments (second mfma operand): z[m][kk*32+q*8 ..+8]
        bfx8 zfrag[4];
#pragma unroll
        for (int kk = 0; kk < 4; ++kk) {
            const float* p = z + (size_t)m * IN_DIM + kk * 32 + q * 8;
            float4 f0 = *(const float4*)p;
            float4 f1 = *(const float4*)(p + 4);
            bfx8 a;
            a[0] = (__bf16)f0.x; a[1] = (__bf16)f0.y; a[2] = (__bf16)f0.z; a[3] = (__bf16)f0.w;
            a[4] = (__bf16)f1.x; a[5] = (__bf16)f1.y; a[6] = (__bf16)f1.z; a[7] = (__bf16)f1.w;
            zfrag[kk] = a;
        }

        f32x4 acc[4];
#pragma unroll
        for (int nt = 0; nt < 4; ++nt) acc[nt] = (f32x4){0.f, 0.f, 0.f, 0.f};

#pragma unroll
        for (int kk = 0; kk < 4; ++kk)
#pragma unroll
            for (int nt = 0; nt < 4; ++nt)
                acc[nt] = __builtin_amdgcn_mfma_f32_16x16x32_bf16(
                    wfrag[nt][kk], zfrag[kk], acc[nt], 0, 0, 0);

        // epilogue: 4 x (bias + cvt + 8 B store). Wave covers 16 rows x 32 B
        // per inst; the 4 waves together fill each row's full 512 B.
#pragma unroll
        for (int nt = 0; nt < 4; ++nt) {
            f32x4 t = acc[nt] + bias[nt];
            bfx4 o;
            o[0] = (__bf16)t[0]; o[1] = (__bf16)t[1];
            o[2] = (__bf16)t[2]; o[3] = (__bf16)t[3];
            *(bfx4*)(UV + (size_t)m * NCOL + n0 + nt * 16 + q * 4) = o;
        }
    }
}

// ---------------- per-edge MLP ----------------
// 16-lane group handles 4 edges (8 independent 16 B gathers in flight/thread).
// lane covers 8 hidden channels; b1 already folded into U.
// h = relu(u+v); out = h . w2 + b2.
__global__ __launch_bounds__(256) void edge_mlp(
    const __bf16* __restrict__ UV, const int* __restrict__ ei,
    const float* __restrict__ W2, const float* __restrict__ b2,
    float* __restrict__ out, int E)
{
    const int gt   = blockIdx.x * blockDim.x + threadIdx.x;
    const int lane = threadIdx.x & 15;
    const int g    = gt >> 4;
    const int e0   = g * 4;
    const int j0   = lane * 8;

    float ww[8];
    {
        float4 w0 = *(const float4*)(W2 + j0);
        float4 w1 = *(const float4*)(W2 + j0 + 4);
        ww[0] = w0.x; ww[1] = w0.y; ww[2] = w0.z; ww[3] = w0.w;
        ww[4] = w1.x; ww[5] = w1.y; ww[6] = w1.z; ww[7] = w1.w;
    }

    if (e0 >= E) return;   // E % 4 == 0

    const int4 s4 = *(const int4*)(ei + e0);       // src of e0..e0+3 (broadcast)
    const int4 d4 = *(const int4*)(ei + E + e0);   // dst of e0..e0+3

    bfx8 u0 = *(const bfx8*)(UV + (size_t)s4.x * NCOL + j0);
    bfx8 u1 = *(const bfx8*)(UV + (size_t)s4.y * NCOL + j0);
    bfx8 u2 = *(const bfx8*)(UV + (size_t)s4.z * NCOL + j0);
    bfx8 u3 = *(const bfx8*)(UV + (size_t)s4.w * NCOL + j0);
    bfx8 v0 = *(const bfx8*)(UV + (size_t)d4.x * NCOL + 128 + j0);
    bfx8 v1 = *(const bfx8*)(UV + (size_t)d4.y * NCOL + 128 + j0);
    bfx8 v2 = *(const bfx8*)(UV + (size_t)d4.z * NCOL + 128 + j0);
    bfx8 v3 = *(const bfx8*)(UV + (size_t)d4.w * NCOL + 128 + j0);

    float s0 = 0.f, s1 = 0.f, s2 = 0.f, s3 = 0.f;
#pragma unroll
    for (int i = 0; i < 8; ++i) {
        s0 = fmaf(fmaxf((float)u0[i] + (float)v0[i], 0.f), ww[i], s0);
        s1 = fmaf(fmaxf((float)u1[i] + (float)v1[i], 0.f), ww[i], s1);
        s2 = fmaf(fmaxf((float)u2[i] + (float)v2[i], 0.f), ww[i], s2);
        s3 = fmaf(fmaxf((float)u3[i] + (float)v3[i], 0.f), ww[i], s3);
    }

#pragma unroll
    for (int d = 1; d < 16; d <<= 1) {
        s0 += __shfl_xor(s0, d);
        s1 += __shfl_xor(s1, d);
        s2 += __shfl_xor(s2, d);
        s3 += __shfl_xor(s3, d);
    }

    if (lane == 0) {
        const float bb = b2[0];
        *(float4*)(out + e0) = make_float4(s0 + bb, s1 + bb, s2 + bb, s3 + bb);
    }
}

extern "C" void kernel_launch(void* const* d_in, const int* in_sizes, int n_in,
                              void* d_out, int out_size, void* d_ws, size_t ws_size,
                              hipStream_t stream)
{
    const float* z  = (const float*)d_in[0];
    const int*   ei = (const int*)d_in[1];
    const float* W1 = (const float*)d_in[2];
    const float* b1 = (const float*)d_in[3];
    const float* W2 = (const float*)d_in[4];
    const float* b2 = (const float*)d_in[5];
    float* out = (float*)d_out;

    const int M = in_sizes[0] / IN_DIM;   // 100000 nodes
    const int E = in_sizes[1] / 2;        // 600000 edges

    __bf16* UV = (__bf16*)d_ws;           // [M][256] bf16 = 51.2 MB

    gemm_mfma<<<M / 32, 256, 0, stream>>>(z, W1, b1, UV, M);   // 3125 blocks

    const int groups  = (E + 3) / 4;                  // 150000
    const int eblocks = (groups * 16 + 255) / 256;    // 9375
    edge_mlp<<<eblocks, 256, 0, stream>>>(UV, ei, W2, b2, out, E);
}

// Round 6
// 182.361 us; speedup vs baseline: 1.1034x; 1.1034x over previous
//
#include <hip/hip_runtime.h>

#define IN_DIM 128
#define NCOL   256   // UV row: [U(128) | V(128)], bf16

typedef __bf16 bfx8 __attribute__((ext_vector_type(8)));
typedef __bf16 bfx4 __attribute__((ext_vector_type(4)));
typedef float  f32x4 __attribute__((ext_vector_type(4)));

// ---------------- pre-pass: Weff = bf16 fused layer-1 weight, [256][128] ----------------
// Weff[n][k] = (n<128) ? W1[n][k] : W1[n-128][128+k]
__global__ __launch_bounds__(256) void prep_w(
    const float* __restrict__ W1, __bf16* __restrict__ Weff)
{
    const int t   = threadIdx.x;
    const int n   = blockIdx.x * 32 + (t >> 3);   // 8 threads per row
    const int k0  = (t & 7) * 16;                 // 16 ch per thread
    const float* src = (n < 128) ? (W1 + n * 256 + k0) : (W1 + (n - 128) * 256 + 128 + k0);
    __bf16* dst = Weff + n * IN_DIM + k0;
#pragma unroll
    for (int k = 0; k < 16; k += 4) {
        float4 f = *(const float4*)(src + k);
        bfx4 b;
        b[0] = (__bf16)f.x; b[1] = (__bf16)f.y; b[2] = (__bf16)f.z; b[3] = (__bf16)f.w;
        *(bfx4*)(dst + k) = b;
    }
}

// ---------------- GEMM: UV = bf16( z @ Weff^T + [b1|0] ) ----------------
// M=100000, K=128, N=256.  MFMA 16x16x32 bf16 with OPERANDS SWAPPED:
//   acc = mfma(wfrag, zfrag, acc)  ->  D[row=q*4+r -> n][col=l15 -> m]
// Each lane's acc f32x4 = 4 consecutive n-values of one m-row: epilogue is
// 4 direct 8 B stores per chunk. No LDS, no barriers anywhere.
// Block = 256 thr = 4 waves; wave w owns n-slice [w*64, w*64+64).
// B-fragments come pre-packed from bf16 Weff: 16 dwordx4 loads, zero cvt.
__global__ __launch_bounds__(256) void gemm_mfma(
    const float* __restrict__ z, const __bf16* __restrict__ Weff,
    const float* __restrict__ b1, __bf16* __restrict__ UV, int M)
{
    const int tid  = threadIdx.x;
    const int wave = tid >> 6;
    const int lane = tid & 63;
    const int l15  = lane & 15;
    const int q    = lane >> 4;        // quad 0..3
    const int n0   = wave * 64;
    const int m0   = blockIdx.x * 32;  // M % 32 == 0

    // --- Weff fragments: lane holds Weff[n0+nt*16+l15][kk*32+q*8 ..+8] (L2-hot) ---
    bfx8 wfrag[4][4];
#pragma unroll
    for (int nt = 0; nt < 4; ++nt) {
        const __bf16* wp = Weff + (n0 + nt * 16 + l15) * IN_DIM + q * 8;
#pragma unroll
        for (int kk = 0; kk < 4; ++kk)
            wfrag[nt][kk] = *(const bfx8*)(wp + kk * 32);
    }

    // --- bias: lane covers n = n0+nt*16+q*4 .. +4 (V half gets 0) ---
    f32x4 bias[4];
#pragma unroll
    for (int nt = 0; nt < 4; ++nt) {
        const int nb = n0 + nt * 16 + q * 4;
        if (nb < 128) {
            float4 b = *(const float4*)(b1 + nb);
            bias[nt] = (f32x4){b.x, b.y, b.z, b.w};
        } else {
            bias[nt] = (f32x4){0.f, 0.f, 0.f, 0.f};
        }
    }

    // --- 2 chunks of 16 m-rows; no barriers -> compiler pipelines freely ---
#pragma unroll
    for (int c = 0; c < 2; ++c) {
        const int m = m0 + c * 16 + l15;

        bfx8 zfrag[4];
#pragma unroll
        for (int kk = 0; kk < 4; ++kk) {
            const float* p = z + (size_t)m * IN_DIM + kk * 32 + q * 8;
            float4 f0 = *(const float4*)p;
            float4 f1 = *(const float4*)(p + 4);
            bfx8 a;
            a[0] = (__bf16)f0.x; a[1] = (__bf16)f0.y; a[2] = (__bf16)f0.z; a[3] = (__bf16)f0.w;
            a[4] = (__bf16)f1.x; a[5] = (__bf16)f1.y; a[6] = (__bf16)f1.z; a[7] = (__bf16)f1.w;
            zfrag[kk] = a;
        }

        f32x4 acc[4];
#pragma unroll
        for (int nt = 0; nt < 4; ++nt) acc[nt] = (f32x4){0.f, 0.f, 0.f, 0.f};

#pragma unroll
        for (int kk = 0; kk < 4; ++kk)
#pragma unroll
            for (int nt = 0; nt < 4; ++nt)
                acc[nt] = __builtin_amdgcn_mfma_f32_16x16x32_bf16(
                    wfrag[nt][kk], zfrag[kk], acc[nt], 0, 0, 0);

        // epilogue: 4 x (bias + cvt + 8 B store), register-direct
#pragma unroll
        for (int nt = 0; nt < 4; ++nt) {
            f32x4 t = acc[nt] + bias[nt];
            bfx4 o;
            o[0] = (__bf16)t[0]; o[1] = (__bf16)t[1];
            o[2] = (__bf16)t[2]; o[3] = (__bf16)t[3];
            *(bfx4*)(UV + (size_t)m * NCOL + n0 + nt * 16 + q * 4) = o;
        }
    }
}

// ---------------- per-edge MLP ----------------
// 16-lane group handles 8 edges (16 independent 16 B gathers in flight/thread).
// lane covers 8 hidden channels; b1 already folded into U.
__global__ __launch_bounds__(256) void edge_mlp(
    const __bf16* __restrict__ UV, const int* __restrict__ ei,
    const float* __restrict__ W2, const float* __restrict__ b2,
    float* __restrict__ out, int E)
{
    const int gt   = blockIdx.x * blockDim.x + threadIdx.x;
    const int lane = threadIdx.x & 15;
    const int g    = gt >> 4;
    const int e0   = g * 8;
    const int j0   = lane * 8;

    float ww[8];
    {
        float4 w0 = *(const float4*)(W2 + j0);
        float4 w1 = *(const float4*)(W2 + j0 + 4);
        ww[0] = w0.x; ww[1] = w0.y; ww[2] = w0.z; ww[3] = w0.w;
        ww[4] = w1.x; ww[5] = w1.y; ww[6] = w1.z; ww[7] = w1.w;
    }

    if (e0 >= E) return;   // E % 8 == 0

    const int4 sa = *(const int4*)(ei + e0);
    const int4 sb = *(const int4*)(ei + e0 + 4);
    const int4 da = *(const int4*)(ei + E + e0);
    const int4 db = *(const int4*)(ei + E + e0 + 4);
    const int sidx[8] = {sa.x, sa.y, sa.z, sa.w, sb.x, sb.y, sb.z, sb.w};
    const int didx[8] = {da.x, da.y, da.z, da.w, db.x, db.y, db.z, db.w};

    bfx8 u[8], v[8];
#pragma unroll
    for (int t = 0; t < 8; ++t) {
        u[t] = *(const bfx8*)(UV + (size_t)sidx[t] * NCOL + j0);
        v[t] = *(const bfx8*)(UV + (size_t)didx[t] * NCOL + 128 + j0);
    }

    float s[8];
#pragma unroll
    for (int t = 0; t < 8; ++t) {
        float acc = 0.f;
#pragma unroll
        for (int i = 0; i < 8; ++i)
            acc = fmaf(fmaxf((float)u[t][i] + (float)v[t][i], 0.f), ww[i], acc);
        s[t] = acc;
    }

#pragma unroll
    for (int d = 1; d < 16; d <<= 1)
#pragma unroll
        for (int t = 0; t < 8; ++t)
            s[t] += __shfl_xor(s[t], d);

    if (lane == 0) {
        const float bb = b2[0];
        float4 o0 = make_float4(s[0] + bb, s[1] + bb, s[2] + bb, s[3] + bb);
        float4 o1 = make_float4(s[4] + bb, s[5] + bb, s[6] + bb, s[7] + bb);
        *(float4*)(out + e0)     = o0;
        *(float4*)(out + e0 + 4) = o1;
    }
}

extern "C" void kernel_launch(void* const* d_in, const int* in_sizes, int n_in,
                              void* d_out, int out_size, void* d_ws, size_t ws_size,
                              hipStream_t stream)
{
    const float* z  = (const float*)d_in[0];
    const int*   ei = (const int*)d_in[1];
    const float* W1 = (const float*)d_in[2];
    const float* b1 = (const float*)d_in[3];
    const float* W2 = (const float*)d_in[4];
    const float* b2 = (const float*)d_in[5];
    float* out = (float*)d_out;

    const int M = in_sizes[0] / IN_DIM;   // 100000 nodes
    const int E = in_sizes[1] / 2;        // 600000 edges

    __bf16* UV   = (__bf16*)d_ws;                 // [M][256] bf16 = 51.2 MB
    __bf16* Weff = UV + (size_t)M * NCOL;         // [256][128] bf16 = 64 KB

    prep_w<<<8, 256, 0, stream>>>(W1, Weff);

    gemm_mfma<<<M / 32, 256, 0, stream>>>(z, Weff, b1, UV, M);   // 3125 blocks

    const int groups  = (E + 7) / 8;                  // 75000
    const int eblocks = (groups * 16 + 255) / 256;    // 4688
    edge_mlp<<<eblocks, 256, 0, stream>>>(UV, ei, W2, b2, out, E);
}

// Round 7
// 176.298 us; speedup vs baseline: 1.1414x; 1.0344x over previous
//
#include <hip/hip_runtime.h>

#define IN_DIM 128
#define NCOL   256          // UV row: [U(128) | V(128)], bf16
#define TPITCH (NCOL + 8)   // LDS tile pitch in bf16 (528 B): 16B-aligned, breaks pow2

typedef __bf16 bfx8 __attribute__((ext_vector_type(8)));
typedef __bf16 bfx4 __attribute__((ext_vector_type(4)));
typedef float  f32x4 __attribute__((ext_vector_type(4)));

// ---------------- pre-pass: Weff = bf16 fused layer-1 weight, [256][128] ----------------
// Weff[n][k] = (n<128) ? W1[n][k] : W1[n-128][128+k]
__global__ __launch_bounds__(256) void prep_w(
    const float* __restrict__ W1, __bf16* __restrict__ Weff)
{
    const int t   = threadIdx.x;
    const int n   = blockIdx.x * 32 + (t >> 3);   // 8 threads per row
    const int k0  = (t & 7) * 16;                 // 16 ch per thread
    const float* src = (n < 128) ? (W1 + n * 256 + k0) : (W1 + (n - 128) * 256 + 128 + k0);
    __bf16* dst = Weff + n * IN_DIM + k0;
#pragma unroll
    for (int k = 0; k < 16; k += 4) {
        float4 f = *(const float4*)(src + k);
        bfx4 b;
        b[0] = (__bf16)f.x; b[1] = (__bf16)f.y; b[2] = (__bf16)f.z; b[3] = (__bf16)f.w;
        *(bfx4*)(dst + k) = b;
    }
}

// ---------------- GEMM: UV = bf16( z @ Weff^T + [b1|0] ) ----------------
// M=100000, K=128, N=256. MFMA 16x16x32 bf16 (standard order: D col=l15->n,
// row=q*4+r->m). Block = 256 thr = 4 waves; wave w owns n-slice [w*64,+64).
// Block covers 64 m-rows as 2 chunks of 32, SOFTWARE-PIPELINED: chunk 1's
// A-loads issue before chunk 0's epilogue barriers, hiding their HBM latency
// under the LDS round-trip + stores. Epilogue = LDS transpose -> 16 B
// coalesced dwordx4 stores (R3's proven-best store path).
__global__ __launch_bounds__(256) void gemm_mfma(
    const float* __restrict__ z, const __bf16* __restrict__ Weff,
    const float* __restrict__ b1, __bf16* __restrict__ UV, int M)
{
    __shared__ __bf16 tile[32][TPITCH];

    const int tid  = threadIdx.x;
    const int wave = tid >> 6;
    const int lane = tid & 63;
    const int l15  = lane & 15;
    const int q    = lane >> 4;        // quad 0..3
    const int n0   = wave * 64;
    const int mbeg = blockIdx.x * 64;  // M % 32 == 0; last block may have 1 chunk

    // --- Weff fragments: lane holds Weff[n0+nt*16+l15][kk*32+q*8 ..+8] (L2-hot) ---
    bfx8 wfrag[4][4];
#pragma unroll
    for (int nt = 0; nt < 4; ++nt) {
        const __bf16* wp = Weff + (n0 + nt * 16 + l15) * IN_DIM + q * 8;
#pragma unroll
        for (int kk = 0; kk < 4; ++kk)
            wfrag[nt][kk] = *(const bfx8*)(wp + kk * 32);
    }

    // --- bias: scalar per nt for this lane's column n = n0+nt*16+l15 ---
    float bias[4];
#pragma unroll
    for (int nt = 0; nt < 4; ++nt) {
        const int n = n0 + nt * 16 + l15;
        bias[nt] = (n < 128) ? b1[n] : 0.f;
    }

    // ---- helpers as macros over locals ----
#define LOAD_A(afrag, mbase)                                                     \
    {                                                                            \
        _Pragma("unroll")                                                        \
        for (int mt = 0; mt < 2; ++mt) {                                         \
            _Pragma("unroll")                                                    \
            for (int kk = 0; kk < 4; ++kk) {                                     \
                const float* p = z + (size_t)((mbase) + mt * 16 + l15) * IN_DIM  \
                                   + kk * 32 + q * 8;                            \
                float4 f0 = *(const float4*)p;                                   \
                float4 f1 = *(const float4*)(p + 4);                             \
                bfx8 a;                                                          \
                a[0] = (__bf16)f0.x; a[1] = (__bf16)f0.y;                        \
                a[2] = (__bf16)f0.z; a[3] = (__bf16)f0.w;                        \
                a[4] = (__bf16)f1.x; a[5] = (__bf16)f1.y;                        \
                a[6] = (__bf16)f1.z; a[7] = (__bf16)f1.w;                        \
                afrag[mt][kk] = a;                                               \
            }                                                                    \
        }                                                                        \
    }

#define MFMA_CHUNK(acc, afrag)                                                   \
    {                                                                            \
        _Pragma("unroll")                                                        \
        for (int mt = 0; mt < 2; ++mt) {                                         \
            _Pragma("unroll")                                                    \
            for (int nt = 0; nt < 4; ++nt) acc[mt][nt] = (f32x4){0.f,0.f,0.f,0.f}; \
        }                                                                        \
        _Pragma("unroll")                                                        \
        for (int kk = 0; kk < 4; ++kk)                                           \
            _Pragma("unroll")                                                    \
            for (int mt = 0; mt < 2; ++mt)                                       \
                _Pragma("unroll")                                                \
                for (int nt = 0; nt < 4; ++nt)                                   \
                    acc[mt][nt] = __builtin_amdgcn_mfma_f32_16x16x32_bf16(       \
                        afrag[mt][kk], wfrag[nt][kk], acc[mt][nt], 0, 0, 0);     \
    }

#define EPILOGUE(acc, mbase)                                                     \
    {                                                                            \
        _Pragma("unroll")                                                        \
        for (int mt = 0; mt < 2; ++mt)                                           \
            _Pragma("unroll")                                                    \
            for (int nt = 0; nt < 4; ++nt) {                                     \
                const int col = n0 + nt * 16 + l15;                              \
                _Pragma("unroll")                                                \
                for (int r = 0; r < 4; ++r)                                      \
                    tile[mt * 16 + q * 4 + r][col] =                             \
                        (__bf16)(acc[mt][nt][r] + bias[nt]);                     \
            }                                                                    \
        __syncthreads();                                                         \
        _Pragma("unroll")                                                        \
        for (int s = 0; s < 4; ++s) {                                            \
            const int lin = s * 256 + tid;                                       \
            const int row = lin >> 5;                                            \
            const int c   = lin & 31;                                            \
            bfx8 v = *(const bfx8*)&tile[row][c * 8];                            \
            *(bfx8*)(UV + (size_t)((mbase) + row) * NCOL + c * 8) = v;           \
        }                                                                        \
        __syncthreads();                                                         \
    }

    bfx8  a0[2][4], a1[2][4];
    f32x4 acc[2][4];
    const bool has2 = (mbeg + 32 < M);

    LOAD_A(a0, mbeg);                 // chunk-0 loads
    MFMA_CHUNK(acc, a0);              // chunk-0 compute (waits on a0)
    if (has2) LOAD_A(a1, mbeg + 32);  // chunk-1 loads in flight BEFORE barriers
    EPILOGUE(acc, mbeg);              // chunk-0 LDS round-trip + stores
    if (has2) {
        MFMA_CHUNK(acc, a1);          // a1 latency hidden under epilogue 0
        EPILOGUE(acc, mbeg + 32);
    }
#undef LOAD_A
#undef MFMA_CHUNK
#undef EPILOGUE
}

// ---------------- per-edge MLP ----------------
// 16-lane group handles 8 edges (16 independent 16 B gathers in flight/thread).
// lane covers 8 hidden channels; b1 already folded into U.
__global__ __launch_bounds__(256) void edge_mlp(
    const __bf16* __restrict__ UV, const int* __restrict__ ei,
    const float* __restrict__ W2, const float* __restrict__ b2,
    float* __restrict__ out, int E)
{
    const int gt   = blockIdx.x * blockDim.x + threadIdx.x;
    const int lane = threadIdx.x & 15;
    const int g    = gt >> 4;
    const int e0   = g * 8;
    const int j0   = lane * 8;

    float ww[8];
    {
        float4 w0 = *(const float4*)(W2 + j0);
        float4 w1 = *(const float4*)(W2 + j0 + 4);
        ww[0] = w0.x; ww[1] = w0.y; ww[2] = w0.z; ww[3] = w0.w;
        ww[4] = w1.x; ww[5] = w1.y; ww[6] = w1.z; ww[7] = w1.w;
    }

    if (e0 >= E) return;   // E % 8 == 0

    const int4 sa = *(const int4*)(ei + e0);
    const int4 sb = *(const int4*)(ei + e0 + 4);
    const int4 da = *(const int4*)(ei + E + e0);
    const int4 db = *(const int4*)(ei + E + e0 + 4);
    const int sidx[8] = {sa.x, sa.y, sa.z, sa.w, sb.x, sb.y, sb.z, sb.w};
    const int didx[8] = {da.x, da.y, da.z, da.w, db.x, db.y, db.z, db.w};

    bfx8 u[8], v[8];
#pragma unroll
    for (int t = 0; t < 8; ++t) {
        u[t] = *(const bfx8*)(UV + (size_t)sidx[t] * NCOL + j0);
        v[t] = *(const bfx8*)(UV + (size_t)didx[t] * NCOL + 128 + j0);
    }

    float s[8];
#pragma unroll
    for (int t = 0; t < 8; ++t) {
        float acc = 0.f;
#pragma unroll
        for (int i = 0; i < 8; ++i)
            acc = fmaf(fmaxf((float)u[t][i] + (float)v[t][i], 0.f), ww[i], acc);
        s[t] = acc;
    }

#pragma unroll
    for (int d = 1; d < 16; d <<= 1)
#pragma unroll
        for (int t = 0; t < 8; ++t)
            s[t] += __shfl_xor(s[t], d);

    if (lane == 0) {
        const float bb = b2[0];
        float4 o0 = make_float4(s[0] + bb, s[1] + bb, s[2] + bb, s[3] + bb);
        float4 o1 = make_float4(s[4] + bb, s[5] + bb, s[6] + bb, s[7] + bb);
        *(float4*)(out + e0)     = o0;
        *(float4*)(out + e0 + 4) = o1;
    }
}

extern "C" void kernel_launch(void* const* d_in, const int* in_sizes, int n_in,
                              void* d_out, int out_size, void* d_ws, size_t ws_size,
                              hipStream_t stream)
{
    const float* z  = (const float*)d_in[0];
    const int*   ei = (const int*)d_in[1];
    const float* W1 = (const float*)d_in[2];
    const float* b1 = (const float*)d_in[3];
    const float* W2 = (const float*)d_in[4];
    const float* b2 = (const float*)d_in[5];
    float* out = (float*)d_out;

    const int M = in_sizes[0] / IN_DIM;   // 100000 nodes
    const int E = in_sizes[1] / 2;        // 600000 edges

    __bf16* UV   = (__bf16*)d_ws;                 // [M][256] bf16 = 51.2 MB
    __bf16* Weff = UV + (size_t)M * NCOL;         // [256][128] bf16 = 64 KB

    prep_w<<<8, 256, 0, stream>>>(W1, Weff);

    const int gblocks = (M + 63) / 64;            // 1563 (last block: 1 chunk)
    gemm_mfma<<<gblocks, 256, 0, stream>>>(z, Weff, b1, UV, M);

    const int groups  = (E + 7) / 8;                  // 75000
    const int eblocks = (groups * 16 + 255) / 256;    // 4688
    edge_mlp<<<eblocks, 256, 0, stream>>>(UV, ei, W2, b2, out, E);
}